// Round 9
// baseline (731.705 us; speedup 1.0000x reference)
//
#include <hip/hip_runtime.h>
#include <hip/hip_bf16.h>
#include <cstddef>

#define H_   22
#define T_   1000
#define B_   64
#define NSEQ (B_ * H_)      // 1408 sequences (B*C, C==22)
#define KP   22             // conv out channels
#define TP   10             // pooled time positions
#define POOL 100
#define CSTR 488            // conv hl row stride in fp16 (484 -> 488 = 61 uint4)
#define XCH  64             // lstm steps per chunk (x load + hs flush granularity)
#define NCHK ((T_ + XCH - 1) / XCH)   // 16 (last chunk = 40 steps)

typedef _Float16 half2_t __attribute__((ext_vector_type(2)));

__device__ __forceinline__ float sigm(float x) {
    return __fdividef(1.f, 1.f + __expf(-x));     // saturates correctly
}

// ---------------------------------------------------------------------------
// Kernel 1: batched independent LSTMs (fp32 in, fp16 hs out).
// ROUND-9 RESTRUCTURE. R6-R8 showed the 2-seq/wave + LDS-h-exchange skeleton
// is chain-bound at ~820 cyc/step with 0.69 waves/SIMD (nothing to hide
// latency). New decomposition:
//  - 1 sequence per wave (1408 waves -> ~1.4/SIMD: dual-resident SIMDs
//    interleave two independent chains).
//  - gate-split: lane u(<22) computes gates i,f; lane 32+u computes g,o
//    (halves dot + transcendental issue). Uniform activation path via
//    tanh(x) = 2*sigm(2x)-1 with per-lane S/A/B constants (no divergence).
//    Gate exchange: 2 ds_bpermute (lane^32); c,h computed redundantly in
//    both halves (identical inputs -> identical results).
//  - h broadcast via v_readlane -> packed SGPRs feeding v_dot2_f32_f16
//    directly: NO LDS round-trip on the chain. Step loop's only DS ops:
//    1 ds_write_b16 (history, fire-and-forget) + 2 bpermute.
//  - x: 64 steps staged in 1 VGPR (coalesced load 1x/chunk), per-step
//    readlane(xv, s). hs flushed from 4KB LDS history once per 64 steps.
// All 64 lanes stay active (no early return): idle lanes (u in [22,32))
// compute garbage and write into hist pad columns; weight loads clamped.
// hs layout: [b][t][c][h] (contiguous 484-elem dot vector per (b,t)).
// ---------------------------------------------------------------------------
__global__ __launch_bounds__(64)
__attribute__((amdgpu_waves_per_eu(2)))
void lstm_k(
    const float* __restrict__ xin,   // [NSEQ][T_]
    const float* __restrict__ W_ih,  // [88]
    const float* __restrict__ W_hh,  // [88][22]
    const float* __restrict__ b_ih,  // [88]
    const float* __restrict__ b_hh,  // [88]
    _Float16* __restrict__ hsw)      // [B_][T_][22][22]
{
    __shared__ __align__(8) _Float16 hist[XCH][32];   // 4 KB: [slot][unit(pad to 32)]
    const int lane = threadIdx.x;
    const int half = lane >> 5;
    const int u    = lane & 31;
    const int u22  = (u < 22) ? u : 21;     // clamp (idle lanes stay active)
    const int seq  = blockIdx.x;
    const int b    = seq / H_;
    const int c    = seq - b * H_;

    // gate rows (PyTorch order i,f,g,o): half0 -> i,f ; half1 -> g,o
    const int row0 = half ? (2 * H_ + u22) : u22;
    const int row1 = half ? (3 * H_ + u22) : (H_ + u22);

    half2_t w20[11], w21[11];
    #pragma unroll
    for (int j = 0; j < 11; ++j) {
        half2_t t;
        t[0] = (_Float16)W_hh[row0 * H_ + 2 * j];
        t[1] = (_Float16)W_hh[row0 * H_ + 2 * j + 1];
        w20[j] = t;
        t[0] = (_Float16)W_hh[row1 * H_ + 2 * j];
        t[1] = (_Float16)W_hh[row1 * H_ + 2 * j + 1];
        w21[j] = t;
    }
    const float wih0 = W_ih[row0], wih1 = W_ih[row1];
    const float bias0 = b_ih[row0] + b_hh[row0];
    const float bias1 = b_ih[row1] + b_hh[row1];

    // activation constants: y = A * 1/(1+exp(S*a)) + B
    //  sigm: S=-1, A=1, B=0 ; tanh: S=-2, A=2, B=-1 (gate0 of half1 = g)
    const float S0 = half ? -2.f : -1.f;
    const float A0 = half ?  2.f :  1.f;
    const float B0 = half ? -1.f :  0.f;
    // gate1 (f / o) is sigmoid in both halves.

    const int pidx = (lane ^ 32) << 2;      // bpermute byte index of partner

    // flush mapping: 55 active lanes = (fa, fj), fa in [0,5), fj in [0,11)
    const int fa = lane / 11, fj = lane - 11 * fa;
    const bool fact = (lane < 55);
    uint* gw = reinterpret_cast<uint*>(hsw);
    const size_t gbase = (size_t)b * T_ * 242 + (size_t)c * 11;

    float hnew = 0.f, creg = 0.f;
    const float* xp = xin + (size_t)seq * T_;
    float xv = (lane < T_) ? xp[lane] : 0.f;   // chunk 0

    for (int chk = 0; chk < NCHK; ++chk) {
        const int t0  = chk * XCH;
        const int nst = (t0 + XCH <= T_) ? XCH : (T_ - t0);

        for (int s = 0; s < nst; ++s) {
            // ---- broadcast h (readlane -> 11 packed f16 pairs, uniform) ----
            const int hfb = __builtin_bit_cast(unsigned short, (_Float16)hnew);
            int ph[11];
            #pragma unroll
            for (int j = 0; j < 11; ++j) {
                const int lo = __builtin_amdgcn_readlane(hfb, 2 * j);
                const int hi = __builtin_amdgcn_readlane(hfb, 2 * j + 1);
                ph[j] = (lo & 0xffff) | (hi << 16);
            }
            const float xc = __uint_as_float(
                __builtin_amdgcn_readlane(__float_as_uint(xv), s));

            // ---- 2 gate dots (11 dot2 each, split 6/5) ----
            float a0 = fmaf(xc, wih0, bias0);
            float a1 = fmaf(xc, wih1, bias1);
            float a0b = 0.f, a1b = 0.f;
            #pragma unroll
            for (int j = 0; j < 6; ++j) {
                const half2_t hp = __builtin_bit_cast(half2_t, ph[j]);
                a0 = __builtin_amdgcn_fdot2(hp, w20[j], a0, false);
                a1 = __builtin_amdgcn_fdot2(hp, w21[j], a1, false);
            }
            #pragma unroll
            for (int j = 6; j < 11; ++j) {
                const half2_t hp = __builtin_bit_cast(half2_t, ph[j]);
                a0b = __builtin_amdgcn_fdot2(hp, w20[j], a0b, false);
                a1b = __builtin_amdgcn_fdot2(hp, w21[j], a1b, false);
            }
            a0 += a0b; a1 += a1b;

            // ---- activations (uniform code path) ----
            const float y0 = fmaf(A0, __fdividef(1.f, 1.f + __expf(S0 * a0)), B0);
            const float y1 = sigm(a1);

            // ---- cross-half exchange: (i,f) <-> (g,o) ----
            const float p0 = __uint_as_float(
                __builtin_amdgcn_ds_bpermute(pidx, __float_as_uint(y0)));
            const float p1 = __uint_as_float(
                __builtin_amdgcn_ds_bpermute(pidx, __float_as_uint(y1)));
            const bool h0 = (half == 0);
            const float iv = h0 ? y0 : p0;
            const float fv = h0 ? y1 : p1;
            const float gv = h0 ? p0 : y0;
            const float ov = h0 ? p1 : y1;

            // ---- state update (redundant in both halves, identical) ----
            creg = fmaf(fv, creg, iv * gv);
            const float th = fmaf(2.f, __fdividef(1.f, 1.f + __expf(-2.f * creg)), -1.f);
            hnew = ov * th;
            hist[s][u] = (_Float16)hnew;   // fire-and-forget (flush reads later)
        }

        // next chunk's x (vmcnt overlaps the flush below)
        const int xi2 = (chk + 1) * XCH + lane;
        const float xnext = (xi2 < T_) ? xp[xi2] : 0.f;

        // ---- flush chunk: hist -> hsw, 704 dwords over 55 lanes ----
        if (fact) {
            #pragma unroll
            for (int i = 0; i < 13; ++i) {
                const int slot = fa + 5 * i;
                if (slot < nst)
                    gw[gbase + (size_t)(t0 + slot) * 242 + fj] =
                        reinterpret_cast<const uint*>(&hist[slot][0])[fj];
            }
        }
        xv = xnext;
    }
}

// ---------------------------------------------------------------------------
// Kernel 2: conv(22ch, kh=22) + bias + ELU + BN(eval) + AvgPool(100).
// One block per (b, pool window p); 256 threads, 220 active: k = tid%22,
// t5 = tid/22 (0..9); each thread: 1 out-channel x 10 rows (t5 + 10i).
// fp16 hs + v_dot2_f32_f16 (__builtin_amdgcn_fdot2): no unpack VALU, 2 MAC
// per op, fp32 accumulate. h-tile LDS reads are wave-broadcast (lanes with
// equal t5 hit the same address). Phased staging 40/40/20 rows.
// ---------------------------------------------------------------------------
__global__ __launch_bounds__(256) void conv_k(
    const _Float16* __restrict__ hsw,        // [B_][T_][22][22]
    const float* __restrict__ conv_w,        // [22][22][22]
    const float* __restrict__ conv_b,        // [22]
    const float* __restrict__ bn_g,
    const float* __restrict__ bn_b,
    const float* __restrict__ bn_m,
    const float* __restrict__ bn_v,
    float* __restrict__ pooled)              // [B_][22][10]
{
    __shared__ __align__(16) _Float16 wl[61 * 22 * 8];  // [cch][k][8]
    __shared__ __align__(16) _Float16 hl[40 * CSTR];
    __shared__ float pp[22 * TP];

    const int tid = threadIdx.x;
    const int b = blockIdx.x / TP;
    const int p = blockIdx.x - b * TP;

    // zero pad elems e=4..7 of chunk 60 (dot positions 484..487)
    if (tid < 22)
        *reinterpret_cast<uint2*>(&wl[(60 * 22 + tid) * 8 + 4]) = make_uint2(0u, 0u);
    // stage conv_w: linear coalesced read; conv_w[k][i][r] -> dot dp=r*22+i,
    // wl[(dp/8)*22 + k][dp%8]
    for (int d = tid; d < 22 * 484; d += 256) {
        const float w = conv_w[d];
        const int k = d / 484, rem = d - k * 484;
        const int i2 = rem / 22, r = rem - i2 * 22;
        const int dp = r * 22 + i2;
        wl[((dp >> 3) * 22 + k) * 8 + (dp & 7)] = (_Float16)w;
    }

    const int k  = tid % 22;          // out channel
    const int t5 = tid / 22;          // row group (0..9 valid)
    const bool act = (tid < 220);

    const float cb = conv_b[k];
    const float mn = bn_m[k];
    const float bt = bn_b[k];
    const float inv = bn_g[k] * __frsqrt_rn(bn_v[k] + 1e-5f);

    float poolsum = 0.f;
    const _Float16* src = hsw + ((size_t)b * T_ + (size_t)p * POOL) * 484;
    const uint4* wl4 = reinterpret_cast<const uint4*>(wl);
    const uint4* hl4 = reinterpret_cast<const uint4*>(hl);

    for (int ph = 0; ph < 3; ++ph) {
        const int rows = (ph == 2) ? 20 : 40;
        const uint2* gsrc = reinterpret_cast<const uint2*>(src + (size_t)(ph * 40) * 484);
        const int n2 = rows * 121;
        for (int idx = tid; idx < n2; idx += 256) {
            const int tr = idx / 121, col = idx - tr * 121;
            reinterpret_cast<uint2*>(&hl[tr * CSTR])[col] = gsrc[idx];
        }
        for (int idx = tid; idx < rows; idx += 256)
            *reinterpret_cast<uint2*>(&hl[idx * CSTR + 484]) = make_uint2(0u, 0u);
        __syncthreads();

        if (act) {
            const int nrt = (ph == 2) ? 2 : 4;     // rows t5 + 10*i
            float acc[4] = {0.f, 0.f, 0.f, 0.f};
            for (int cch = 0; cch < 61; ++cch) {
                const uint4 wv = wl4[cch * 22 + k];
                const half2_t* w2 = reinterpret_cast<const half2_t*>(&wv);
                for (int i = 0; i < nrt; ++i) {
                    const uint4 hv = hl4[(t5 + 10 * i) * 61 + cch];
                    const half2_t* h2 = reinterpret_cast<const half2_t*>(&hv);
                    acc[i] = __builtin_amdgcn_fdot2(h2[0], w2[0], acc[i], false);
                    acc[i] = __builtin_amdgcn_fdot2(h2[1], w2[1], acc[i], false);
                    acc[i] = __builtin_amdgcn_fdot2(h2[2], w2[2], acc[i], false);
                    acc[i] = __builtin_amdgcn_fdot2(h2[3], w2[3], acc[i], false);
                }
            }
            const int nv = (ph == 2) ? 2 : 4;
            for (int i = 0; i < nv; ++i) {
                const float s = acc[i] + cb;
                const float e = (s > 0.f) ? s : (__expf(s) - 1.f);
                poolsum += fmaf(e - mn, inv, bt);
            }
        }
        __syncthreads();
    }

    if (act) pp[k * TP + t5] = poolsum;
    __syncthreads();
    if (tid < 22) {
        float s = 0.f;
        #pragma unroll
        for (int q = 0; q < TP; ++q) s += pp[tid * TP + q];
        pooled[((size_t)b * 22 + tid) * TP + p] = s * 0.01f;
    }
}

// ---------------------------------------------------------------------------
// Kernel 3: FC [64,220] x [220,4]^T + bias -> fp32 out. One thread per output.
// ---------------------------------------------------------------------------
__global__ __launch_bounds__(256) void fc_k(
    const float* __restrict__ pooled,  // [64][220] (idx = k*10+p)
    const float* __restrict__ fc_w,    // [4][220]
    const float* __restrict__ fc_b,    // [4]
    float* __restrict__ out)           // [64][4]
{
    const int tid = threadIdx.x;
    const int b = tid >> 2, n = tid & 3;
    const float* pv = pooled + b * 220;
    const float* wv = fc_w + n * 220;
    float s = fc_b[n];
    #pragma unroll 4
    for (int j = 0; j < 220; ++j)
        s = fmaf(pv[j], wv[j], s);
    out[tid] = s;
}

extern "C" void kernel_launch(void* const* d_in, const int* in_sizes, int n_in,
                              void* d_out, int out_size, void* d_ws, size_t ws_size,
                              hipStream_t stream) {
    const float* xin    = (const float*)d_in[0];
    const float* W_ih   = (const float*)d_in[1];
    const float* W_hh   = (const float*)d_in[2];
    const float* b_ih   = (const float*)d_in[3];
    const float* b_hh   = (const float*)d_in[4];
    const float* conv_w = (const float*)d_in[5];
    const float* conv_b = (const float*)d_in[6];
    const float* bn_g   = (const float*)d_in[7];
    const float* bn_b   = (const float*)d_in[8];
    const float* bn_m   = (const float*)d_in[9];
    const float* bn_v   = (const float*)d_in[10];
    const float* fc_w   = (const float*)d_in[11];
    const float* fc_b   = (const float*)d_in[12];

    _Float16* hsw = (_Float16*)d_ws;                                    // 61,952,000 B
    float* pooled = (float*)((char*)d_ws + (size_t)B_ * T_ * 484 * 2);  // 56,320 B

    lstm_k<<<NSEQ, 64, 0, stream>>>(xin, W_ih, W_hh, b_ih, b_hh, hsw);
    conv_k<<<B_ * TP, 256, 0, stream>>>(hsw, conv_w, conv_b, bn_g, bn_b, bn_m, bn_v, pooled);
    fc_k<<<1, 256, 0, stream>>>(pooled, fc_w, fc_b, (float*)d_out);
}

// Round 10
// 725.901 us; speedup vs baseline: 1.0080x; 1.0080x over previous
//
#include <hip/hip_runtime.h>
#include <hip/hip_bf16.h>
#include <cstddef>

#define H_   22
#define T_   1000
#define B_   64
#define NSEQ (B_ * H_)      // 1408 sequences (B*C, C==22)
#define KP   22             // conv out channels
#define TP   10             // pooled time positions
#define POOL 100
#define CSTR 488            // conv hl row stride in fp16 (484 -> 488 = 61 uint4)
#define XCH  64             // lstm steps per chunk (x load + hs flush granularity)
#define NCHK ((T_ + XCH - 1) / XCH)   // 16 (last chunk = 40 steps)

typedef _Float16 half2_t __attribute__((ext_vector_type(2)));

__device__ __forceinline__ float sigm(float x) {
    return __fdividef(1.f, 1.f + __expf(-x));     // saturates correctly
}

// ---------------------------------------------------------------------------
// Kernel 1: batched independent LSTMs (fp32 in, fp16 hs out).
// Structure (validated for correctness in R9):
//  - 1 sequence per wave (1408 waves -> ~1.4/SIMD: dual-resident SIMDs
//    interleave two independent serial chains).
//  - gate-split: lane u(<22) computes gates i,f; lane 32+u computes g,o.
//    Uniform activation path via tanh(x) = 2*sigm(2x)-1 with per-lane
//    S/A/B constants. Gate exchange: 2 ds_bpermute (lane^32); c,h
//    computed redundantly in both halves.
//  - h broadcast via v_readlane -> packed SGPRs feeding v_dot2_f32_f16.
//  - x: 64 steps staged in 1 VGPR; hs flushed from LDS hist 1x/64 steps.
//
// ROUND-10 FIX: R9 used amdgpu_waves_per_eu(2) — SINGLE ARG = MIN ONLY.
// Allocator chased max occupancy (VGPR_Count=32 < the ~45 needed) and
// rematerialized the 22 packed weight VGPRs as per-step global loads:
// L2-resident (8KB table) so FETCH stayed flat, but ~200cyc L2-hit latency
// landed on the serial chain EVERY step (+600 cyc/step). (2,2) pins
// min=max=2 waves/EU -> 256-VGPR budget, weights resident, and keeps
// 2-wave co-residency for chain interleaving.
// hs layout: [b][t][c][h] (contiguous 484-elem dot vector per (b,t)).
// ---------------------------------------------------------------------------
__global__ __launch_bounds__(64)
__attribute__((amdgpu_waves_per_eu(2, 2)))
void lstm_k(
    const float* __restrict__ xin,   // [NSEQ][T_]
    const float* __restrict__ W_ih,  // [88]
    const float* __restrict__ W_hh,  // [88][22]
    const float* __restrict__ b_ih,  // [88]
    const float* __restrict__ b_hh,  // [88]
    _Float16* __restrict__ hsw)      // [B_][T_][22][22]
{
    __shared__ __align__(8) _Float16 hist[XCH][32];   // 4 KB: [slot][unit(pad to 32)]
    const int lane = threadIdx.x;
    const int half = lane >> 5;
    const int u    = lane & 31;
    const int u22  = (u < 22) ? u : 21;     // clamp (idle lanes stay active)
    const int seq  = blockIdx.x;
    const int b    = seq / H_;
    const int c    = seq - b * H_;

    // gate rows (PyTorch order i,f,g,o): half0 -> i,f ; half1 -> g,o
    const int row0 = half ? (2 * H_ + u22) : u22;
    const int row1 = half ? (3 * H_ + u22) : (H_ + u22);

    half2_t w20[11], w21[11];
    #pragma unroll
    for (int j = 0; j < 11; ++j) {
        half2_t t;
        t[0] = (_Float16)W_hh[row0 * H_ + 2 * j];
        t[1] = (_Float16)W_hh[row0 * H_ + 2 * j + 1];
        w20[j] = t;
        t[0] = (_Float16)W_hh[row1 * H_ + 2 * j];
        t[1] = (_Float16)W_hh[row1 * H_ + 2 * j + 1];
        w21[j] = t;
    }
    const float wih0 = W_ih[row0], wih1 = W_ih[row1];
    const float bias0 = b_ih[row0] + b_hh[row0];
    const float bias1 = b_ih[row1] + b_hh[row1];

    // activation constants: y = A * 1/(1+exp(S*a)) + B
    //  sigm: S=-1, A=1, B=0 ; tanh: S=-2, A=2, B=-1 (gate0 of half1 = g)
    const float S0 = half ? -2.f : -1.f;
    const float A0 = half ?  2.f :  1.f;
    const float B0 = half ? -1.f :  0.f;
    // gate1 (f / o) is sigmoid in both halves.

    const int pidx = (lane ^ 32) << 2;      // bpermute byte index of partner

    // flush mapping: 55 active lanes = (fa, fj), fa in [0,5), fj in [0,11)
    const int fa = lane / 11, fj = lane - 11 * fa;
    const bool fact = (lane < 55);
    uint* gw = reinterpret_cast<uint*>(hsw);
    const size_t gbase = (size_t)b * T_ * 242 + (size_t)c * 11;

    float hnew = 0.f, creg = 0.f;
    const float* xp = xin + (size_t)seq * T_;
    float xv = (lane < T_) ? xp[lane] : 0.f;   // chunk 0

    for (int chk = 0; chk < NCHK; ++chk) {
        const int t0  = chk * XCH;
        const int nst = (t0 + XCH <= T_) ? XCH : (T_ - t0);

        for (int s = 0; s < nst; ++s) {
            // ---- broadcast h (readlane -> 11 packed f16 pairs, uniform) ----
            const int hfb = __builtin_bit_cast(unsigned short, (_Float16)hnew);
            int ph[11];
            #pragma unroll
            for (int j = 0; j < 11; ++j) {
                const int lo = __builtin_amdgcn_readlane(hfb, 2 * j);
                const int hi = __builtin_amdgcn_readlane(hfb, 2 * j + 1);
                ph[j] = (lo & 0xffff) | (hi << 16);
            }
            const float xc = __uint_as_float(
                __builtin_amdgcn_readlane(__float_as_uint(xv), s));

            // ---- 2 gate dots (11 dot2 each, split 6/5) ----
            float a0 = fmaf(xc, wih0, bias0);
            float a1 = fmaf(xc, wih1, bias1);
            float a0b = 0.f, a1b = 0.f;
            #pragma unroll
            for (int j = 0; j < 6; ++j) {
                const half2_t hp = __builtin_bit_cast(half2_t, ph[j]);
                a0 = __builtin_amdgcn_fdot2(hp, w20[j], a0, false);
                a1 = __builtin_amdgcn_fdot2(hp, w21[j], a1, false);
            }
            #pragma unroll
            for (int j = 6; j < 11; ++j) {
                const half2_t hp = __builtin_bit_cast(half2_t, ph[j]);
                a0b = __builtin_amdgcn_fdot2(hp, w20[j], a0b, false);
                a1b = __builtin_amdgcn_fdot2(hp, w21[j], a1b, false);
            }
            a0 += a0b; a1 += a1b;

            // ---- activations (uniform code path) ----
            const float y0 = fmaf(A0, __fdividef(1.f, 1.f + __expf(S0 * a0)), B0);
            const float y1 = sigm(a1);

            // ---- cross-half exchange: (i,f) <-> (g,o) ----
            const float p0 = __uint_as_float(
                __builtin_amdgcn_ds_bpermute(pidx, __float_as_uint(y0)));
            const float p1 = __uint_as_float(
                __builtin_amdgcn_ds_bpermute(pidx, __float_as_uint(y1)));
            const bool h0 = (half == 0);
            const float iv = h0 ? y0 : p0;
            const float fv = h0 ? y1 : p1;
            const float gv = h0 ? p0 : y0;
            const float ov = h0 ? p1 : y1;

            // ---- state update (redundant in both halves, identical) ----
            creg = fmaf(fv, creg, iv * gv);
            const float th = fmaf(2.f, __fdividef(1.f, 1.f + __expf(-2.f * creg)), -1.f);
            hnew = ov * th;
            hist[s][u] = (_Float16)hnew;   // fire-and-forget (flush reads later)
        }

        // next chunk's x (vmcnt overlaps the flush below)
        const int xi2 = (chk + 1) * XCH + lane;
        const float xnext = (xi2 < T_) ? xp[xi2] : 0.f;

        // ---- flush chunk: hist -> hsw, 704 dwords over 55 lanes ----
        if (fact) {
            #pragma unroll
            for (int i = 0; i < 13; ++i) {
                const int slot = fa + 5 * i;
                if (slot < nst)
                    gw[gbase + (size_t)(t0 + slot) * 242 + fj] =
                        reinterpret_cast<const uint*>(&hist[slot][0])[fj];
            }
        }
        xv = xnext;
    }
}

// ---------------------------------------------------------------------------
// Kernel 2: conv(22ch, kh=22) + bias + ELU + BN(eval) + AvgPool(100).
// One block per (b, pool window p); 256 threads, 220 active: k = tid%22,
// t5 = tid/22 (0..9); each thread: 1 out-channel x 10 rows (t5 + 10i).
// fp16 hs + v_dot2_f32_f16 (__builtin_amdgcn_fdot2): no unpack VALU, 2 MAC
// per op, fp32 accumulate. h-tile LDS reads are wave-broadcast (lanes with
// equal t5 hit the same address). Phased staging 40/40/20 rows.
// ---------------------------------------------------------------------------
__global__ __launch_bounds__(256) void conv_k(
    const _Float16* __restrict__ hsw,        // [B_][T_][22][22]
    const float* __restrict__ conv_w,        // [22][22][22]
    const float* __restrict__ conv_b,        // [22]
    const float* __restrict__ bn_g,
    const float* __restrict__ bn_b,
    const float* __restrict__ bn_m,
    const float* __restrict__ bn_v,
    float* __restrict__ pooled)              // [B_][22][10]
{
    __shared__ __align__(16) _Float16 wl[61 * 22 * 8];  // [cch][k][8]
    __shared__ __align__(16) _Float16 hl[40 * CSTR];
    __shared__ float pp[22 * TP];

    const int tid = threadIdx.x;
    const int b = blockIdx.x / TP;
    const int p = blockIdx.x - b * TP;

    // zero pad elems e=4..7 of chunk 60 (dot positions 484..487)
    if (tid < 22)
        *reinterpret_cast<uint2*>(&wl[(60 * 22 + tid) * 8 + 4]) = make_uint2(0u, 0u);
    // stage conv_w: linear coalesced read; conv_w[k][i][r] -> dot dp=r*22+i,
    // wl[(dp/8)*22 + k][dp%8]
    for (int d = tid; d < 22 * 484; d += 256) {
        const float w = conv_w[d];
        const int k = d / 484, rem = d - k * 484;
        const int i2 = rem / 22, r = rem - i2 * 22;
        const int dp = r * 22 + i2;
        wl[((dp >> 3) * 22 + k) * 8 + (dp & 7)] = (_Float16)w;
    }

    const int k  = tid % 22;          // out channel
    const int t5 = tid / 22;          // row group (0..9 valid)
    const bool act = (tid < 220);

    const float cb = conv_b[k];
    const float mn = bn_m[k];
    const float bt = bn_b[k];
    const float inv = bn_g[k] * __frsqrt_rn(bn_v[k] + 1e-5f);

    float poolsum = 0.f;
    const _Float16* src = hsw + ((size_t)b * T_ + (size_t)p * POOL) * 484;
    const uint4* wl4 = reinterpret_cast<const uint4*>(wl);
    const uint4* hl4 = reinterpret_cast<const uint4*>(hl);

    for (int ph = 0; ph < 3; ++ph) {
        const int rows = (ph == 2) ? 20 : 40;
        const uint2* gsrc = reinterpret_cast<const uint2*>(src + (size_t)(ph * 40) * 484);
        const int n2 = rows * 121;
        for (int idx = tid; idx < n2; idx += 256) {
            const int tr = idx / 121, col = idx - tr * 121;
            reinterpret_cast<uint2*>(&hl[tr * CSTR])[col] = gsrc[idx];
        }
        for (int idx = tid; idx < rows; idx += 256)
            *reinterpret_cast<uint2*>(&hl[idx * CSTR + 484]) = make_uint2(0u, 0u);
        __syncthreads();

        if (act) {
            const int nrt = (ph == 2) ? 2 : 4;     // rows t5 + 10*i
            float acc[4] = {0.f, 0.f, 0.f, 0.f};
            for (int cch = 0; cch < 61; ++cch) {
                const uint4 wv = wl4[cch * 22 + k];
                const half2_t* w2 = reinterpret_cast<const half2_t*>(&wv);
                for (int i = 0; i < nrt; ++i) {
                    const uint4 hv = hl4[(t5 + 10 * i) * 61 + cch];
                    const half2_t* h2 = reinterpret_cast<const half2_t*>(&hv);
                    acc[i] = __builtin_amdgcn_fdot2(h2[0], w2[0], acc[i], false);
                    acc[i] = __builtin_amdgcn_fdot2(h2[1], w2[1], acc[i], false);
                    acc[i] = __builtin_amdgcn_fdot2(h2[2], w2[2], acc[i], false);
                    acc[i] = __builtin_amdgcn_fdot2(h2[3], w2[3], acc[i], false);
                }
            }
            const int nv = (ph == 2) ? 2 : 4;
            for (int i = 0; i < nv; ++i) {
                const float s = acc[i] + cb;
                const float e = (s > 0.f) ? s : (__expf(s) - 1.f);
                poolsum += fmaf(e - mn, inv, bt);
            }
        }
        __syncthreads();
    }

    if (act) pp[k * TP + t5] = poolsum;
    __syncthreads();
    if (tid < 22) {
        float s = 0.f;
        #pragma unroll
        for (int q = 0; q < TP; ++q) s += pp[tid * TP + q];
        pooled[((size_t)b * 22 + tid) * TP + p] = s * 0.01f;
    }
}

// ---------------------------------------------------------------------------
// Kernel 3: FC [64,220] x [220,4]^T + bias -> fp32 out. One thread per output.
// ---------------------------------------------------------------------------
__global__ __launch_bounds__(256) void fc_k(
    const float* __restrict__ pooled,  // [64][220] (idx = k*10+p)
    const float* __restrict__ fc_w,    // [4][220]
    const float* __restrict__ fc_b,    // [4]
    float* __restrict__ out)           // [64][4]
{
    const int tid = threadIdx.x;
    const int b = tid >> 2, n = tid & 3;
    const float* pv = pooled + b * 220;
    const float* wv = fc_w + n * 220;
    float s = fc_b[n];
    #pragma unroll 4
    for (int j = 0; j < 220; ++j)
        s = fmaf(pv[j], wv[j], s);
    out[tid] = s;
}

extern "C" void kernel_launch(void* const* d_in, const int* in_sizes, int n_in,
                              void* d_out, int out_size, void* d_ws, size_t ws_size,
                              hipStream_t stream) {
    const float* xin    = (const float*)d_in[0];
    const float* W_ih   = (const float*)d_in[1];
    const float* W_hh   = (const float*)d_in[2];
    const float* b_ih   = (const float*)d_in[3];
    const float* b_hh   = (const float*)d_in[4];
    const float* conv_w = (const float*)d_in[5];
    const float* conv_b = (const float*)d_in[6];
    const float* bn_g   = (const float*)d_in[7];
    const float* bn_b   = (const float*)d_in[8];
    const float* bn_m   = (const float*)d_in[9];
    const float* bn_v   = (const float*)d_in[10];
    const float* fc_w   = (const float*)d_in[11];
    const float* fc_b   = (const float*)d_in[12];

    _Float16* hsw = (_Float16*)d_ws;                                    // 61,952,000 B
    float* pooled = (float*)((char*)d_ws + (size_t)B_ * T_ * 484 * 2);  // 56,320 B

    lstm_k<<<NSEQ, 64, 0, stream>>>(xin, W_ih, W_hh, b_ih, b_hh, hsw);
    conv_k<<<B_ * TP, 256, 0, stream>>>(hsw, conv_w, conv_b, bn_g, bn_b, bn_m, bn_v, pooled);
    fc_k<<<1, 256, 0, stream>>>(pooled, fc_w, fc_b, (float*)d_out);
}